// Round 1
// baseline (1423.694 us; speedup 1.0000x reference)
//
#include <hip/hip_runtime.h>
#include <hip/hip_bf16.h>

// ---------------------------------------------------------------------------
// TransformerBlock: B=2 S=2048 D=1024 NH=16 HD=64 FF=4096
// Round 1: correct full pipeline, bf16 MFMA GEMMs (m92-style 128x128 tiles),
// 3-pass attention (stats / coalesced attn-write / PV), fp32 residuals.
// ---------------------------------------------------------------------------

constexpr int Bc = 2, Sc = 2048, Dc = 1024, NHc = 16, FFc = 4096;
constexpr int Mrows = Bc * Sc;              // 4096
constexpr float SCALE_ = 0.125f;            // HD^-0.5
constexpr float EPSc = 1e-5f;
constexpr float L2E = 1.4426950408889634f;
constexpr float SC_L2E = SCALE_ * L2E;

typedef __attribute__((ext_vector_type(8))) short short8;
typedef __attribute__((ext_vector_type(4))) short short4v;
typedef __attribute__((ext_vector_type(4))) float floatx4;

#define DEV static __device__ __forceinline__

DEV short f2b(float f) {                    // fp32 -> bf16 (RNE), raw bits
  union { float f; unsigned u; } v; v.f = f;
  unsigned r = v.u + 0x7FFFu + ((v.u >> 16) & 1u);
  return (short)(r >> 16);
}

DEV floatx4 mfma16(short8 a, short8 b, floatx4 c) {
  return __builtin_amdgcn_mfma_f32_16x16x32_bf16(a, b, c, 0, 0, 0);
}

// ---------------------------------------------------------------------------
// Weight cast + transpose: W (K,N) fp32 -> Wt (N,K) bf16
// ---------------------------------------------------------------------------
__global__ __launch_bounds__(256) void cast_transpose_k(
    const float* __restrict__ W, short* __restrict__ Wt, int K, int N) {
  __shared__ float t[32][33];
  int n0 = blockIdx.x * 32, k0 = blockIdx.y * 32;
  int tx = threadIdx.x & 31, ty = threadIdx.x >> 5;
  for (int r = ty; r < 32; r += 8)
    t[r][tx] = W[(size_t)(k0 + r) * N + n0 + tx];
  __syncthreads();
  for (int r = ty; r < 32; r += 8)
    Wt[(size_t)(n0 + r) * K + k0 + tx] = f2b(t[tx][r]);
}

// ---------------------------------------------------------------------------
// LayerNorm over D=1024, fp32 in -> bf16 out. One block (256 thr) per row.
// ---------------------------------------------------------------------------
__global__ __launch_bounds__(256) void layernorm_k(
    const float* __restrict__ x, const float* __restrict__ g,
    const float* __restrict__ bb, short* __restrict__ out) {
  int row = blockIdx.x;
  float4 v = ((const float4*)(x + (size_t)row * Dc))[threadIdx.x];
  float s = v.x + v.y + v.z + v.w;
  float s2 = v.x * v.x + v.y * v.y + v.z * v.z + v.w * v.w;
#pragma unroll
  for (int off = 32; off >= 1; off >>= 1) {
    s += __shfl_xor(s, off);
    s2 += __shfl_xor(s2, off);
  }
  __shared__ float red[8];
  int wave = threadIdx.x >> 6, lane = threadIdx.x & 63;
  if (lane == 0) { red[wave] = s; red[4 + wave] = s2; }
  __syncthreads();
  s = red[0] + red[1] + red[2] + red[3];
  s2 = red[4] + red[5] + red[6] + red[7];
  float mu = s * (1.0f / Dc);
  float var = s2 * (1.0f / Dc) - mu * mu;
  float rstd = rsqrtf(var + EPSc);
  int c = threadIdx.x * 4;
  float4 gv = ((const float4*)g)[threadIdx.x];
  float4 bv = ((const float4*)bb)[threadIdx.x];
  short4v o;
  o.x = f2b((v.x - mu) * rstd * gv.x + bv.x);
  o.y = f2b((v.y - mu) * rstd * gv.y + bv.y);
  o.z = f2b((v.z - mu) * rstd * gv.z + bv.z);
  o.w = f2b((v.w - mu) * rstd * gv.w + bv.w);
  *(short4v*)(out + (size_t)row * Dc + c) = o;
}

// ---------------------------------------------------------------------------
// GEMM: C(MxN) = A(MxK,bf16) @ Bt(NxK,bf16)^T  [+bias] [+resid fp32] [relu]
// 128x128 block tile, BK=32, 4 waves -> 64x64 quadrants, 16x16x32 MFMA.
// OUTF==0: bf16 out, OUTF==1: fp32 out.
// ---------------------------------------------------------------------------
template <int OUTF>
__global__ __launch_bounds__(256) void gemm_bt_k(
    const short* __restrict__ A, const short* __restrict__ Bt,
    const float* __restrict__ bias, const float* __restrict__ resid,
    void* __restrict__ Cout, int M, int N, int K, int relu) {
  constexpr int PAD = 40;                   // 80B rows: 16B aligned, ~2-way banks
  __shared__ short As[128 * PAD];
  __shared__ short Bs[128 * PAD];
  int tid = threadIdx.x;
  int wave = tid >> 6, lane = tid & 63, quad = lane >> 4, l16 = lane & 15;
  int m0 = blockIdx.y * 128, n0 = blockIdx.x * 128;
  int wm = (wave & 1) * 64, wn = (wave >> 1) * 64;
  int srow = tid >> 1, scol = (tid & 1) * 16;
  floatx4 acc[4][4] = {};
  for (int k0 = 0; k0 < K; k0 += 32) {
    const short8* ap = (const short8*)(A + (size_t)(m0 + srow) * K + k0 + scol);
    short8 a0 = ap[0], a1 = ap[1];
    const short8* bp = (const short8*)(Bt + (size_t)(n0 + srow) * K + k0 + scol);
    short8 b0 = bp[0], b1 = bp[1];
    __syncthreads();
    *(short8*)(&As[srow * PAD + scol]) = a0;
    *(short8*)(&As[srow * PAD + scol + 8]) = a1;
    *(short8*)(&Bs[srow * PAD + scol]) = b0;
    *(short8*)(&Bs[srow * PAD + scol + 8]) = b1;
    __syncthreads();
    short8 af[4], bf[4];
#pragma unroll
    for (int i = 0; i < 4; ++i)
      af[i] = *(const short8*)(&As[(wm + i * 16 + l16) * PAD + quad * 8]);
#pragma unroll
    for (int j = 0; j < 4; ++j)
      bf[j] = *(const short8*)(&Bs[(wn + j * 16 + l16) * PAD + quad * 8]);
#pragma unroll
    for (int i = 0; i < 4; ++i)
#pragma unroll
      for (int j = 0; j < 4; ++j)
        acc[i][j] = mfma16(af[i], bf[j], acc[i][j]);
  }
#pragma unroll
  for (int i = 0; i < 4; ++i) {
    int row = m0 + wm + i * 16 + quad * 4;
#pragma unroll
    for (int j = 0; j < 4; ++j) {
      int col = n0 + wn + j * 16 + l16;
      float bv = bias ? bias[col] : 0.0f;
#pragma unroll
      for (int r = 0; r < 4; ++r) {
        float v = acc[i][j][r] + bv;
        if (resid) v += resid[(size_t)(row + r) * N + col];
        if (relu) v = fmaxf(v, 0.0f);
        if (OUTF == 0)
          ((short*)Cout)[(size_t)(row + r) * N + col] = f2b(v);
        else
          ((float*)Cout)[(size_t)(row + r) * N + col] = v;
      }
    }
  }
}

// ---------------------------------------------------------------------------
// vT[b][h][d][m] = kv[b][m][1024 + h*64 + d]   (bf16, for PV B-operand)
// ---------------------------------------------------------------------------
__global__ __launch_bounds__(256) void transpose_v_k(
    const short* __restrict__ kv, short* __restrict__ vT) {
  __shared__ short t[64][65];
  int bh = blockIdx.y, b = bh >> 4, h = bh & 15;
  int m0 = blockIdx.x * 64;
  int c = threadIdx.x & 63, ty = threadIdx.x >> 6;
  for (int r = ty; r < 64; r += 4)
    t[r][c] = kv[(size_t)(b * Sc + m0 + r) * 2048 + 1024 + h * 64 + c];
  __syncthreads();
  for (int dd = ty; dd < 64; dd += 4)
    vT[((size_t)bh * 64 + dd) * Sc + m0 + c] = t[c][dd];
}

// ---------------------------------------------------------------------------
// Attention pass 1: row max (log2-domain, incl. scale) + sumexp2 -> m_i, 1/l
// grid (S/64, B*NH); each wave owns 16 query rows, streams all m via MFMA.
// ---------------------------------------------------------------------------
__global__ __launch_bounds__(256) void attn_stats_k(
    const short* __restrict__ q, const short* __restrict__ kv,
    float* __restrict__ m_i, float* __restrict__ inv_l) {
  int bh = blockIdx.y, b = bh >> 4, h = bh & 15;
  int wave = threadIdx.x >> 6, lane = threadIdx.x & 63, quad = lane >> 4,
      l16 = lane & 15;
  int n0 = blockIdx.x * 64 + wave * 16;
  const short* qp = q + (size_t)(b * Sc + n0 + l16) * Dc + h * 64 + quad * 8;
  short8 qf0 = *(const short8*)qp;
  short8 qf1 = *(const short8*)(qp + 32);
  const short* kb = kv + (size_t)b * Sc * 2048 + h * 64 + quad * 8;
  float rm[4], rl[4];
#pragma unroll
  for (int r = 0; r < 4; ++r) { rm[r] = -1e30f; rl[r] = 0.0f; }
  for (int m0 = 0; m0 < Sc; m0 += 16) {
    const short* kp = kb + (size_t)(m0 + l16) * 2048;
    short8 kf0 = *(const short8*)kp;
    short8 kf1 = *(const short8*)(kp + 32);
    floatx4 s = {0.0f, 0.0f, 0.0f, 0.0f};
    s = mfma16(qf0, kf0, s);
    s = mfma16(qf1, kf1, s);
#pragma unroll
    for (int r = 0; r < 4; ++r) {
      float sv = s[r] * SC_L2E;
      if (sv <= rm[r]) {
        rl[r] += exp2f(sv - rm[r]);
      } else {
        rl[r] = rl[r] * exp2f(rm[r] - sv) + 1.0f;
        rm[r] = sv;
      }
    }
  }
#pragma unroll
  for (int off = 1; off < 16; off <<= 1) {
#pragma unroll
    for (int r = 0; r < 4; ++r) {
      float om = __shfl_xor(rm[r], off);
      float ol = __shfl_xor(rl[r], off);
      float nm = fmaxf(rm[r], om);
      rl[r] = rl[r] * exp2f(rm[r] - nm) + ol * exp2f(om - nm);
      rm[r] = nm;
    }
  }
  if (l16 == 0) {
    int n = n0 + quad * 4;
#pragma unroll
    for (int r = 0; r < 4; ++r) {
      m_i[(size_t)bh * Sc + n + r] = rm[r];
      inv_l[(size_t)bh * Sc + n + r] = 1.0f / rl[r];
    }
  }
}

// ---------------------------------------------------------------------------
// Attention pass 2a: write attn[b][n][m][h] fp32, coalesced.
// Block covers (b, n-tile 32, m-tile 16, ALL 16 heads); wave w -> heads 4w..4w+3.
// P gathered in LDS [n][m][h] then stored as contiguous 1KB rows.
// ---------------------------------------------------------------------------
__global__ __launch_bounds__(256) void attn_write_k(
    const short* __restrict__ q, const short* __restrict__ kv,
    const float* __restrict__ m_i, const float* __restrict__ inv_l,
    float* __restrict__ attn) {
  constexpr int HP = 17;
  __shared__ float P[32 * 16 * HP];         // 34816 B
  __shared__ float sm[16][32], sl[16][32];  // stats for n0..n0+31, all h
  int b = blockIdx.z;
  int n0 = blockIdx.y * 32, m0 = blockIdx.x * 16;
  int tid = threadIdx.x;
  int wave = tid >> 6, lane = tid & 63, quad = lane >> 4, l16 = lane & 15;
  for (int i = tid; i < 512; i += 256) {
    int h = i >> 5, nn = i & 31;
    sm[h][nn] = m_i[(size_t)(b * 16 + h) * Sc + n0 + nn];
    sl[h][nn] = inv_l[(size_t)(b * 16 + h) * Sc + n0 + nn];
  }
  __syncthreads();
#pragma unroll
  for (int hh = 0; hh < 4; ++hh) {
    int h = wave * 4 + hh;
    const short* kp = kv + (size_t)(b * Sc + m0 + l16) * 2048 + h * 64 + quad * 8;
    short8 kf0 = *(const short8*)kp;
    short8 kf1 = *(const short8*)(kp + 32);
#pragma unroll
    for (int ni = 0; ni < 2; ++ni) {
      const short* qp =
          q + (size_t)(b * Sc + n0 + ni * 16 + l16) * Dc + h * 64 + quad * 8;
      short8 qf0 = *(const short8*)qp;
      short8 qf1 = *(const short8*)(qp + 32);
      floatx4 s = {0.0f, 0.0f, 0.0f, 0.0f};
      s = mfma16(qf0, kf0, s);
      s = mfma16(qf1, kf1, s);
#pragma unroll
      for (int r = 0; r < 4; ++r) {
        int nn = ni * 16 + quad * 4 + r;
        float p = exp2f(s[r] * SC_L2E - sm[h][nn]) * sl[h][nn];
        P[(nn * 16 + l16) * HP + h] = p;
      }
    }
  }
  __syncthreads();
  size_t base = ((size_t)(b * Sc + n0) * Sc + m0) * 16;
  int m = tid >> 4, h = tid & 15;           // 16m x 16h = 256
  for (int n = 0; n < 32; ++n)
    attn[base + (size_t)n * (Sc * 16) + m * 16 + h] = P[(n * 16 + m) * HP + h];
}

// ---------------------------------------------------------------------------
// Attention pass 2b: o[b][n][h*64+d] = softmax(qk) @ v, per (b,h); recompute S,
// P via per-wave LDS C->A layout round-trip, PV with vT. inv_l folded at end.
// ---------------------------------------------------------------------------
__global__ __launch_bounds__(256) void attn_pv_k(
    const short* __restrict__ q, const short* __restrict__ kv,
    const short* __restrict__ vT, const float* __restrict__ m_i,
    const float* __restrict__ inv_l, short* __restrict__ o) {
  constexpr int PPAD = 40;                  // 80B rows, 16B aligned
  __shared__ short P[4][16 * PPAD];
  int bh = blockIdx.y, b = bh >> 4, h = bh & 15;
  int wave = threadIdx.x >> 6, lane = threadIdx.x & 63, quad = lane >> 4,
      l16 = lane & 15;
  int n0 = blockIdx.x * 64 + wave * 16;
  const short* qp = q + (size_t)(b * Sc + n0 + l16) * Dc + h * 64 + quad * 8;
  short8 qf0 = *(const short8*)qp;
  short8 qf1 = *(const short8*)(qp + 32);
  float mm[4], il[4];
#pragma unroll
  for (int r = 0; r < 4; ++r) {
    int n = n0 + quad * 4 + r;
    mm[r] = m_i[(size_t)bh * Sc + n];
    il[r] = inv_l[(size_t)bh * Sc + n];
  }
  floatx4 oacc[4] = {};
  const short* kb = kv + (size_t)b * Sc * 2048 + h * 64 + quad * 8;
  const short* vb = vT + (size_t)bh * 64 * Sc;
  short* myP = &P[wave][0];
  for (int m0 = 0; m0 < Sc; m0 += 32) {
#pragma unroll
    for (int ms = 0; ms < 2; ++ms) {
      const short* kp = kb + (size_t)(m0 + ms * 16 + l16) * 2048;
      short8 kf0 = *(const short8*)kp;
      short8 kf1 = *(const short8*)(kp + 32);
      floatx4 s = {0.0f, 0.0f, 0.0f, 0.0f};
      s = mfma16(qf0, kf0, s);
      s = mfma16(qf1, kf1, s);
#pragma unroll
      for (int r = 0; r < 4; ++r) {
        float p = exp2f(s[r] * SC_L2E - mm[r]);  // <= 1, unnormalized
        myP[(quad * 4 + r) * PPAD + ms * 16 + l16] = f2b(p);
      }
    }
    short8 pf = *(const short8*)(&myP[l16 * PPAD + quad * 8]);
#pragma unroll
    for (int ds = 0; ds < 4; ++ds) {
      short8 vf = *(const short8*)(vb + (size_t)(ds * 16 + l16) * Sc + m0 + quad * 8);
      oacc[ds] = mfma16(pf, vf, oacc[ds]);
    }
  }
#pragma unroll
  for (int ds = 0; ds < 4; ++ds)
#pragma unroll
    for (int r = 0; r < 4; ++r)
      o[(size_t)(b * Sc + n0 + quad * 4 + r) * Dc + h * 64 + ds * 16 + l16] =
          f2b(oacc[ds][r] * il[r]);
}

// ---------------------------------------------------------------------------
extern "C" void kernel_launch(void* const* d_in, const int* in_sizes, int n_in,
                              void* d_out, int out_size, void* d_ws,
                              size_t ws_size, hipStream_t stream) {
  const float* x = (const float*)d_in[0];
  const float* ln1g = (const float*)d_in[1];
  const float* ln1b = (const float*)d_in[2];
  const float* wq = (const float*)d_in[3];
  const float* wkv = (const float*)d_in[4];
  const float* wo = (const float*)d_in[5];
  const float* bo = (const float*)d_in[6];
  const float* ln2g = (const float*)d_in[7];
  const float* ln2b = (const float*)d_in[8];
  const float* w1 = (const float*)d_in[9];
  const float* b1 = (const float*)d_in[10];
  const float* w2 = (const float*)d_in[11];
  const float* b2 = (const float*)d_in[12];

  char* ws = (char*)d_ws;
  const size_t MB = 1024 * 1024;
  short* wqT  = (short*)(ws + 0 * MB);       // 2 MB
  short* wkvT = (short*)(ws + 2 * MB);       // 4 MB
  short* woT  = (short*)(ws + 6 * MB);       // 2 MB
  short* w1T  = (short*)(ws + 8 * MB);       // 8 MB
  short* w2T  = (short*)(ws + 16 * MB);      // 8 MB
  short* h    = (short*)(ws + 24 * MB);      // 8 MB (reused as h2)
  float* x2   = (float*)(ws + 32 * MB);      // 16 MB
  float* m_i  = (float*)(ws + 48 * MB);      // 256 KB
  float* invl = (float*)(ws + 48 * MB + 256 * 1024);  // 256 KB
  short* o    = (short*)(ws + 49 * MB);      // 8 MB
  short* qb   = (short*)(ws + 57 * MB);      // 8 MB  -+
  short* kvb  = (short*)(ws + 65 * MB);      // 16 MB  | overlaid by ff1 later
  short* vT   = (short*)(ws + 81 * MB);      // 8 MB  -+
  short* ff1  = (short*)(ws + 57 * MB);      // 32 MB (after attention done)

  float* out0 = (float*)d_out;
  float* attn = (float*)d_out + (size_t)Bc * Sc * Dc;

  // weights -> bf16, transposed (N x K)
  cast_transpose_k<<<dim3(Dc / 32, Dc / 32), 256, 0, stream>>>(wq, wqT, Dc, Dc);
  cast_transpose_k<<<dim3(2048 / 32, Dc / 32), 256, 0, stream>>>(wkv, wkvT, Dc, 2048);
  cast_transpose_k<<<dim3(Dc / 32, Dc / 32), 256, 0, stream>>>(wo, woT, Dc, Dc);
  cast_transpose_k<<<dim3(FFc / 32, Dc / 32), 256, 0, stream>>>(w1, w1T, Dc, FFc);
  cast_transpose_k<<<dim3(Dc / 32, FFc / 32), 256, 0, stream>>>(w2, w2T, FFc, Dc);

  layernorm_k<<<Mrows, 256, 0, stream>>>(x, ln1g, ln1b, h);

  gemm_bt_k<0><<<dim3(Dc / 128, Mrows / 128), 256, 0, stream>>>(
      h, wqT, nullptr, nullptr, qb, Mrows, Dc, Dc, 0);
  gemm_bt_k<0><<<dim3(2048 / 128, Mrows / 128), 256, 0, stream>>>(
      h, wkvT, nullptr, nullptr, kvb, Mrows, 2048, Dc, 0);

  transpose_v_k<<<dim3(Sc / 64, Bc * NHc), 256, 0, stream>>>(kvb, vT);
  attn_stats_k<<<dim3(Sc / 64, Bc * NHc), 256, 0, stream>>>(qb, kvb, m_i, invl);
  attn_write_k<<<dim3(Sc / 16, Sc / 32, Bc), 256, 0, stream>>>(qb, kvb, m_i, invl, attn);
  attn_pv_k<<<dim3(Sc / 64, Bc * NHc), 256, 0, stream>>>(qb, kvb, vT, m_i, invl, o);

  gemm_bt_k<1><<<dim3(Dc / 128, Mrows / 128), 256, 0, stream>>>(
      o, woT, bo, x, x2, Mrows, Dc, Dc, 0);
  layernorm_k<<<Mrows, 256, 0, stream>>>(x2, ln2g, ln2b, h);
  gemm_bt_k<0><<<dim3(FFc / 128, Mrows / 128), 256, 0, stream>>>(
      h, w1T, b1, nullptr, ff1, Mrows, FFc, Dc, 1);
  gemm_bt_k<1><<<dim3(Dc / 128, Mrows / 128), 256, 0, stream>>>(
      ff1, w2T, b2, x2, out0, Mrows, Dc, FFc, 0);
}